// Round 2
// baseline (430.708 us; speedup 1.0000x reference)
//
#include <hip/hip_runtime.h>
#include <math.h>

namespace {
constexpr int NBINS = 8;
constexpr int HW4 = (512 * 512) / 4;   // float4s per (b,c) plane
constexpr int PLANES = 16 * 3;         // B*C
// ln((double)1.01f); 1.01f == 1.0099999904632568359375
constexpr double LN_BASE = 0.0099503214108481;
// correctly-rounded powf(1.01f,z) > 1.0f  <=>  true value > 1 + 2^-24 (tie->even->1.0)
constexpr double KEEP_THRESH = 1.0 + 1.0 / 16777216.0;
// log2(1.01f) — value path only needs ~2e-2 accuracy
constexpr float LOG2_BASE = 0.014355293f;

typedef float v4f __attribute__((ext_vector_type(4)));

__device__ __forceinline__ float binval(float z) {
  if (!(z > 0.0f)) return 0.0f;
  if (z < 1.0e-5f) {
    // Near the fp32 rounding boundary of powf(1.01f, z) at 1.0: decide in double.
    double p = exp((double)z * LN_BASE);
    if (!(p > KEEP_THRESH)) return 0.0f;
  }
  return exp2f(z * LOG2_BASE);
}
}  // namespace

__global__ __launch_bounds__(256) void hist_kernel(
    const float4* __restrict__ in, const float* __restrict__ centers,
    const float* __restrict__ wptr, float* __restrict__ out) {
  const int plane = blockIdx.y;                    // b*C + c
  const int i4 = blockIdx.x * 256 + threadIdx.x;   // float4 index in plane
  const float w = wptr[0];
  float c[NBINS];
#pragma unroll
  for (int k = 0; k < NBINS; ++k) c[k] = centers[k];

  const float4 x = in[(size_t)plane * HW4 + i4];
  v4f* const out2 = reinterpret_cast<v4f*>(out + PLANES * NBINS) +
                    (size_t)plane * NBINS * HW4 + i4;
  float sums[NBINS];
#pragma unroll
  for (int k = 0; k < NBINS; ++k) {
    v4f v;
    v.x = binval(w - fabsf(x.x - c[k]));
    v.y = binval(w - fabsf(x.y - c[k]));
    v.z = binval(w - fabsf(x.z - c[k]));
    v.w = binval(w - fabsf(x.w - c[k]));
    __builtin_nontemporal_store(v, out2 + (size_t)k * HW4);
    sums[k] = (v.x + v.y) + (v.z + v.w);
  }

  // block reduction: wave shuffle -> LDS across 4 waves -> 8 atomics/block
#pragma unroll
  for (int k = 0; k < NBINS; ++k) {
#pragma unroll
    for (int off = 32; off > 0; off >>= 1)
      sums[k] += __shfl_down(sums[k], off, 64);
  }
  __shared__ float part[4][NBINS];
  const int lane = threadIdx.x & 63;
  const int wv = threadIdx.x >> 6;
  if (lane == 0) {
#pragma unroll
    for (int k = 0; k < NBINS; ++k) part[wv][k] = sums[k];
  }
  __syncthreads();
  if (threadIdx.x < NBINS) {
    float s = (part[0][threadIdx.x] + part[1][threadIdx.x]) +
              (part[2][threadIdx.x] + part[3][threadIdx.x]);
    atomicAdd(out + plane * NBINS + threadIdx.x, s * (1.0f / 262144.0f));
  }
}

extern "C" void kernel_launch(void* const* d_in, const int* in_sizes, int n_in,
                              void* d_out, int out_size, void* d_ws, size_t ws_size,
                              hipStream_t stream) {
  const float4* in = (const float4*)d_in[0];
  const float* centers = (const float*)d_in[1];
  const float* width = (const float*)d_in[2];
  float* out = (float*)d_out;
  // one_d region (first 384 floats) accumulates via atomics — zero it each call
  (void)hipMemsetAsync(d_out, 0, PLANES * NBINS * sizeof(float), stream);
  hist_kernel<<<dim3(256, PLANES), 256, 0, stream>>>(in, centers, width, out);
}